// Round 11
// baseline (24409.225 us; speedup 1.0000x reference)
//
#include <hip/hip_runtime.h>
#include <hip/hip_bf16.h>

#define T_STEPS 512
#define BATCH   64
#define HID     1024

typedef __attribute__((ext_vector_type(8))) short short8;
typedef __attribute__((ext_vector_type(4))) float f32x4;

static __device__ __forceinline__ float b2f(unsigned short u){
  union { unsigned u; float f; } c; c.u = ((unsigned)u) << 16; return c.f;
}
static __device__ __forceinline__ unsigned short f2b(float f){
  union { float f; unsigned u; } c; c.f = f;
  unsigned r = c.u + 0x7fffu + ((c.u >> 16) & 1u);
  return (unsigned short)(r >> 16);
}
static __device__ __forceinline__ float sigm(float x){ return 1.0f / (1.0f + __expf(-x)); }
static __device__ __forceinline__ float tanh_fast(float x){ return 2.0f / (1.0f + __expf(-2.0f * x)) - 1.0f; }

#define MFMA __builtin_amdgcn_mfma_f32_16x16x32_bf16

// ---------------- init: zero H state (bf16 + fp32) ----------------
__global__ void gru_init_k(unsigned short* __restrict__ hbf, float* __restrict__ hf32){
  int i = blockIdx.x * blockDim.x + threadIdx.x;
  if (i < BATCH * HID){ hbf[i] = 0; hf32[i] = 0.f; }
}

// ---------------- transpose + cast weights: Wt[g][n][k] = W_g[k][n] ----------------
__global__ void gru_prepw_k(const float* __restrict__ w0, const float* __restrict__ w1,
                            const float* __restrict__ w2, const float* __restrict__ w3,
                            const float* __restrict__ w4, const float* __restrict__ w5,
                            unsigned short* __restrict__ wt){
  __shared__ float tile[32][33];
  const float* src;
  switch (blockIdx.z){
    case 0: src = w0; break; case 1: src = w1; break; case 2: src = w2; break;
    case 3: src = w3; break; case 4: src = w4; break; default: src = w5; break;
  }
  int tx = threadIdx.x, ty = threadIdx.y;
  int x0 = blockIdx.x * 32, y0 = blockIdx.y * 32;
  #pragma unroll
  for (int i = 0; i < 32; i += 8)
    tile[ty + i][tx] = src[(size_t)(y0 + ty + i) * HID + x0 + tx];
  __syncthreads();
  unsigned short* dst = wt + (size_t)blockIdx.z * HID * HID;
  #pragma unroll
  for (int i = 0; i < 32; i += 8)
    dst[(size_t)(x0 + ty + i) * HID + y0 + tx] = f2b(tile[tx][ty + i]);
}

// ---------------- pre-pass: G2[t][gate][col][row] = (X @ Wx + b), bf16 ----------
__global__ __launch_bounds__(256, 2) void gru_xproj_k(
    const float* __restrict__ inp,         // [32768][1024] fp32
    const unsigned short* __restrict__ wt, // x-weights slots 0,2,4
    const float* __restrict__ bz, const float* __restrict__ br, const float* __restrict__ bh,
    unsigned short* __restrict__ G2)       // [512][3][1024][64] bf16
{
  const int wv = threadIdx.x >> 6, lane = threadIdx.x & 63;
  const int l16 = lane & 15, kq = lane >> 4;
  const int m0 = blockIdx.x * 64;
  const int n0 = blockIdx.y * 256 + wv * 64;

  const unsigned short* wb[4];
  float bias[4];
  #pragma unroll
  for (int c = 0; c < 4; ++c){
    int n = n0 + c * 16 + l16;
    int g = n >> 10, cc = n & 1023;
    wb[c] = wt + (size_t)(2 * g) * HID * HID + (size_t)cc * HID + kq * 8;
    bias[c] = (g == 0 ? bz : (g == 1 ? br : bh))[cc];
  }
  const float* arow[4];
  #pragma unroll
  for (int r = 0; r < 4; ++r)
    arow[r] = inp + (size_t)(m0 + r * 16 + l16) * HID + kq * 8;

  f32x4 acc[4][4];
  #pragma unroll
  for (int r = 0; r < 4; ++r)
    #pragma unroll
    for (int c = 0; c < 4; ++c) acc[r][c] = (f32x4){0.f,0.f,0.f,0.f};

  #pragma unroll 2
  for (int kk = 0; kk < HID; kk += 32){
    short8 af[4], bf[4];
    #pragma unroll
    for (int r = 0; r < 4; ++r){
      float4 f0 = *(const float4*)(arow[r] + kk);
      float4 f1 = *(const float4*)(arow[r] + kk + 4);
      short8 a;
      a[0]=(short)f2b(f0.x); a[1]=(short)f2b(f0.y); a[2]=(short)f2b(f0.z); a[3]=(short)f2b(f0.w);
      a[4]=(short)f2b(f1.x); a[5]=(short)f2b(f1.y); a[6]=(short)f2b(f1.z); a[7]=(short)f2b(f1.w);
      af[r] = a;
    }
    #pragma unroll
    for (int c = 0; c < 4; ++c) bf[c] = *(const short8*)(wb[c] + kk);
    #pragma unroll
    for (int r = 0; r < 4; ++r)
      #pragma unroll
      for (int c = 0; c < 4; ++c)
        acc[r][c] = MFMA(af[r], bf[c], acc[r][c], 0, 0, 0);
  }

  #pragma unroll
  for (int c = 0; c < 4; ++c){
    int n = n0 + c * 16 + l16;
    int g = n >> 10, cc = n & 1023;
    #pragma unroll
    for (int r = 0; r < 4; ++r){
      unsigned lo = (unsigned)f2b(acc[r][c][0] + bias[c]) | ((unsigned)f2b(acc[r][c][1] + bias[c]) << 16);
      unsigned hi = (unsigned)f2b(acc[r][c][2] + bias[c]) | ((unsigned)f2b(acc[r][c][3] + bias[c]) << 16);
      *(unsigned long long*)&G2[((size_t)(blockIdx.x * 3 + g) * 1024 + cc) * 64 + r * 16 + kq * 4] =
        (unsigned long long)lo | ((unsigned long long)hi << 32);
    }
  }
}

// ---------------- step phase A: Z and R gates + R*H (one kernel, 32 WGs) ----------------
// blockIdx.x: 0-15 -> Z cols [bid*64,+64); 16-31 -> R cols [(bid-16)*64,+64)
__global__ __launch_bounds__(256) void gru_stepA_k(
    const unsigned short* __restrict__ G2,
    const unsigned short* __restrict__ wt,
    const unsigned short* __restrict__ hbf,   // H_{t-1} bf16 [64][1024]
    const float* __restrict__ hf32,           // H_{t-1} fp32 [64][1024]
    float* __restrict__ zbuf,                 // Z fp32 [64][1024]
    unsigned short* __restrict__ rhbf,        // R*H bf16 [64][1024]
    int t)
{
  const int wv = threadIdx.x >> 6, lane = threadIdx.x & 63;
  const int l16 = lane & 15, kq = lane >> 4;
  const int g = blockIdx.x >> 4;                       // 0=Z, 1=R
  const int c = (blockIdx.x & 15) * 64 + wv * 16 + l16;

  const unsigned short* wb = wt + (size_t)(g ? 3 : 1) * HID * HID + (size_t)c * HID + kq * 8;
  const unsigned short* ab = hbf + kq * 8;

  f32x4 acc[4];
  #pragma unroll
  for (int r = 0; r < 4; ++r) acc[r] = (f32x4){0.f,0.f,0.f,0.f};

  #pragma unroll 8
  for (int kk = 0; kk < HID; kk += 32){
    short8 bf = *(const short8*)(wb + kk);
    #pragma unroll
    for (int r = 0; r < 4; ++r){
      short8 af = *(const short8*)(ab + (size_t)(r * 16 + l16) * HID + kk);
      acc[r] = MFMA(af, bf, acc[r], 0, 0, 0);
    }
  }

  const size_t gbase = (((size_t)t * 3 + g) * 1024 + c) * 64;
  #pragma unroll
  for (int r = 0; r < 4; ++r){
    int row0 = r * 16 + kq * 4;
    unsigned long long u = *(const unsigned long long*)(G2 + gbase + row0);
    #pragma unroll
    for (int j = 0; j < 4; ++j){
      float v = sigm(acc[r][j] + b2f((unsigned short)(u >> (16 * j))));
      size_t idx = (size_t)(row0 + j) * HID + c;
      if (g == 0) zbuf[idx] = v;
      else        rhbf[idx] = f2b(v * hf32[idx]);
    }
  }
}

// ---------------- step phase B: H_tilde + combine + publish H_t (16 WGs) ----------------
__global__ __launch_bounds__(256) void gru_stepB_k(
    const unsigned short* __restrict__ G2,
    const unsigned short* __restrict__ wt,
    const unsigned short* __restrict__ rhbf,
    const float* __restrict__ zbuf,
    float* __restrict__ hf32,
    unsigned short* __restrict__ hbf,
    float* __restrict__ out,
    int t)
{
  const int wv = threadIdx.x >> 6, lane = threadIdx.x & 63;
  const int l16 = lane & 15, kq = lane >> 4;
  const int c = blockIdx.x * 64 + wv * 16 + l16;

  const unsigned short* wb = wt + (size_t)5 * HID * HID + (size_t)c * HID + kq * 8;
  const unsigned short* ab = rhbf + kq * 8;

  f32x4 acc[4];
  #pragma unroll
  for (int r = 0; r < 4; ++r) acc[r] = (f32x4){0.f,0.f,0.f,0.f};

  #pragma unroll 8
  for (int kk = 0; kk < HID; kk += 32){
    short8 bf = *(const short8*)(wb + kk);
    #pragma unroll
    for (int r = 0; r < 4; ++r){
      short8 af = *(const short8*)(ab + (size_t)(r * 16 + l16) * HID + kk);
      acc[r] = MFMA(af, bf, acc[r], 0, 0, 0);
    }
  }

  const size_t gbase = (((size_t)t * 3 + 2) * 1024 + c) * 64;
  #pragma unroll
  for (int r = 0; r < 4; ++r){
    int row0 = r * 16 + kq * 4;
    unsigned long long u = *(const unsigned long long*)(G2 + gbase + row0);
    #pragma unroll
    for (int j = 0; j < 4; ++j){
      int row = row0 + j;
      size_t idx = (size_t)row * HID + c;
      float ht = tanh_fast(acc[r][j] + b2f((unsigned short)(u >> (16 * j))));
      float z  = zbuf[idx];
      float hp = hf32[idx];
      float hn = z * hp + (1.0f - z) * ht;
      hf32[idx] = hn;
      hbf[idx]  = f2b(hn);
      out[((size_t)t * BATCH + row) * HID + c] = hn;
      if (t == T_STEPS - 1)
        out[(size_t)T_STEPS * BATCH * HID + idx] = hn;
    }
  }
}

extern "C" void kernel_launch(void* const* d_in, const int* in_sizes, int n_in,
                              void* d_out, int out_size, void* d_ws, size_t ws_size,
                              hipStream_t stream){
  const float* inputs = (const float*)d_in[0];
  const float* W_xz = (const float*)d_in[1];
  const float* W_hz = (const float*)d_in[2];
  const float* b_z  = (const float*)d_in[3];
  const float* W_xr = (const float*)d_in[4];
  const float* W_hr = (const float*)d_in[5];
  const float* b_r  = (const float*)d_in[6];
  const float* W_xh = (const float*)d_in[7];
  const float* W_hh = (const float*)d_in[8];
  const float* b_h  = (const float*)d_in[9];
  float* out = (float*)d_out;

  char* ws = (char*)d_ws;
  float*          zbuf = (float*)ws;                              // 256 KiB
  unsigned short* rhbf = (unsigned short*)(ws + 262144);          // 128 KiB
  unsigned short* hbf  = (unsigned short*)(ws + 393216);          // 128 KiB
  float*          hf32 = (float*)(ws + 524288);                   // 256 KiB
  unsigned short* wt   = (unsigned short*)(ws + 786432);          // 12 MiB
  unsigned short* G2   = (unsigned short*)(ws + 786432 + 12582912); // 192 MiB
  // total ws needed: ~206 MB

  gru_init_k<<<256, 256, 0, stream>>>(hbf, hf32);
  gru_prepw_k<<<dim3(32, 32, 6), dim3(32, 8), 0, stream>>>(W_xz, W_hz, W_xr, W_hr, W_xh, W_hh, wt);
  gru_xproj_k<<<dim3(512, 12), 256, 0, stream>>>(inputs, wt, b_z, b_r, b_h, G2);

  for (int t = 0; t < T_STEPS; ++t){
    gru_stepA_k<<<32, 256, 0, stream>>>(G2, wt, hbf, hf32, zbuf, rhbf, t);
    gru_stepB_k<<<16, 256, 0, stream>>>(G2, wt, rhbf, zbuf, hf32, hbf, out, t);
  }
}

// Round 12
// 15206.618 us; speedup vs baseline: 1.6052x; 1.6052x over previous
//
#include <hip/hip_runtime.h>
#include <hip/hip_bf16.h>

#define T_STEPS 512
#define BATCH   64
#define HID     1024
#define NWG     32          // 4 row-groups x 8 col-slices
#define NSLOT   32          // rotating exchange slots
#define SLOT_SH (4 * 16 * 1024)   // shorts per slot (4 row-groups x 16 x 1024)

typedef __attribute__((ext_vector_type(8))) short short8;
typedef __attribute__((ext_vector_type(4))) float f32x4;
typedef __attribute__((ext_vector_type(4))) int  i32x4;

static __device__ __forceinline__ float b2f(unsigned short u){
  union { unsigned u; float f; } c; c.u = ((unsigned)u) << 16; return c.f;
}
static __device__ __forceinline__ unsigned short f2b(float f){
  union { float f; unsigned u; } c; c.f = f;
  unsigned r = c.u + 0x7fffu + ((c.u >> 16) & 1u);
  return (unsigned short)(r >> 16);
}
static __device__ __forceinline__ float sigm(float x){ return 1.0f / (1.0f + __expf(-x)); }
static __device__ __forceinline__ float tanh_fast(float x){ return 2.0f / (1.0f + __expf(-2.0f * x)) - 1.0f; }

#define MFMA __builtin_amdgcn_mfma_f32_16x16x32_bf16

// ---------------- init: zero barrier flags (1 flag per 128B line) ----------------
__global__ void gru_init_k(int* __restrict__ flags){
  int i = blockIdx.x * blockDim.x + threadIdx.x;
  if (i < NWG * 32)
    __hip_atomic_store(flags + i, 0, __ATOMIC_RELAXED, __HIP_MEMORY_SCOPE_AGENT);
}

// ---------------- transpose + cast weights: Wt[g][n][k] = W_g[k][n] ----------------
__global__ void gru_prepw_k(const float* __restrict__ w0, const float* __restrict__ w1,
                            const float* __restrict__ w2, const float* __restrict__ w3,
                            const float* __restrict__ w4, const float* __restrict__ w5,
                            unsigned short* __restrict__ wt){
  __shared__ float tile[32][33];
  const float* src;
  switch (blockIdx.z){
    case 0: src = w0; break; case 1: src = w1; break; case 2: src = w2; break;
    case 3: src = w3; break; case 4: src = w4; break; default: src = w5; break;
  }
  int tx = threadIdx.x, ty = threadIdx.y;
  int x0 = blockIdx.x * 32, y0 = blockIdx.y * 32;
  #pragma unroll
  for (int i = 0; i < 32; i += 8)
    tile[ty + i][tx] = src[(size_t)(y0 + ty + i) * HID + x0 + tx];
  __syncthreads();
  unsigned short* dst = wt + (size_t)blockIdx.z * HID * HID;
  #pragma unroll
  for (int i = 0; i < 32; i += 8)
    dst[(size_t)(x0 + ty + i) * HID + y0 + tx] = f2b(tile[tx][ty + i]);
}

// ---------------- pre-pass: G2[t][gate][col][row] = (X @ Wx + b), bf16 ----------
__global__ __launch_bounds__(256, 2) void gru_xproj_k(
    const float* __restrict__ inp,         // [32768][1024] fp32
    const unsigned short* __restrict__ wt, // x-weights slots 0,2,4
    const float* __restrict__ bz, const float* __restrict__ br, const float* __restrict__ bh,
    unsigned short* __restrict__ G2)       // [512][3][1024][64] bf16
{
  const int wv = threadIdx.x >> 6, lane = threadIdx.x & 63;
  const int l16 = lane & 15, kq = lane >> 4;
  const int m0 = blockIdx.x * 64;
  const int n0 = blockIdx.y * 256 + wv * 64;

  const unsigned short* wb[4];
  float bias[4];
  #pragma unroll
  for (int c = 0; c < 4; ++c){
    int n = n0 + c * 16 + l16;
    int g = n >> 10, cc = n & 1023;
    wb[c] = wt + (size_t)(2 * g) * HID * HID + (size_t)cc * HID + kq * 8;
    bias[c] = (g == 0 ? bz : (g == 1 ? br : bh))[cc];
  }
  const float* arow[4];
  #pragma unroll
  for (int r = 0; r < 4; ++r)
    arow[r] = inp + (size_t)(m0 + r * 16 + l16) * HID + kq * 8;

  f32x4 acc[4][4];
  #pragma unroll
  for (int r = 0; r < 4; ++r)
    #pragma unroll
    for (int c = 0; c < 4; ++c) acc[r][c] = (f32x4){0.f,0.f,0.f,0.f};

  #pragma unroll 2
  for (int kk = 0; kk < HID; kk += 32){
    short8 af[4], bf[4];
    #pragma unroll
    for (int r = 0; r < 4; ++r){
      float4 f0 = *(const float4*)(arow[r] + kk);
      float4 f1 = *(const float4*)(arow[r] + kk + 4);
      short8 a;
      a[0]=(short)f2b(f0.x); a[1]=(short)f2b(f0.y); a[2]=(short)f2b(f0.z); a[3]=(short)f2b(f0.w);
      a[4]=(short)f2b(f1.x); a[5]=(short)f2b(f1.y); a[6]=(short)f2b(f1.z); a[7]=(short)f2b(f1.w);
      af[r] = a;
    }
    #pragma unroll
    for (int c = 0; c < 4; ++c) bf[c] = *(const short8*)(wb[c] + kk);
    #pragma unroll
    for (int r = 0; r < 4; ++r)
      #pragma unroll
      for (int c = 0; c < 4; ++c)
        acc[r][c] = MFMA(af[r], bf[c], acc[r][c], 0, 0, 0);
  }

  #pragma unroll
  for (int c = 0; c < 4; ++c){
    int n = n0 + c * 16 + l16;
    int g = n >> 10, cc = n & 1023;
    #pragma unroll
    for (int r = 0; r < 4; ++r){
      unsigned lo = (unsigned)f2b(acc[r][c][0] + bias[c]) | ((unsigned)f2b(acc[r][c][1] + bias[c]) << 16);
      unsigned hi = (unsigned)f2b(acc[r][c][2] + bias[c]) | ((unsigned)f2b(acc[r][c][3] + bias[c]) << 16);
      *(unsigned long long*)&G2[((size_t)(blockIdx.x * 3 + g) * 1024 + cc) * 64 + r * 16 + kq * 4] =
        (unsigned long long)lo | ((unsigned long long)hi << 32);
    }
  }
}

// ---- poll: 8 lanes, one flag each (flags 128B apart), s_sleep backoff ----
static __device__ __forceinline__ void waitflags8(const int* fgrp, int target){
  const int lane = threadIdx.x & 63;
  const int* p = fgrp + (lane & 7) * 32;
  const bool mine = lane < 8;
  for (;;){
    int v = mine ? __hip_atomic_load(p, __ATOMIC_RELAXED, __HIP_MEMORY_SCOPE_AGENT)
                 : 0x7fffffff;
    if (__all(v >= target)) return;
    __builtin_amdgcn_s_sleep(2);
  }
}

// ---- stage 16x1024 bf16 tile (32KB) via CACHED nontemporal loads (fresh slot lines) ----
static __device__ __forceinline__ void stage_in(const unsigned short* __restrict__ src,
                                                unsigned short* __restrict__ stg, int tid){
  const int lin = tid * 32;                 // shorts (64B per thread)
  const int sw  = ((tid >> 5) & 7) << 4;    // byte XOR (row&7)<<4
  const short8* s = (const short8*)(src + lin);
  short8 v0 = __builtin_nontemporal_load(s);
  short8 v1 = __builtin_nontemporal_load(s + 1);
  short8 v2 = __builtin_nontemporal_load(s + 2);
  short8 v3 = __builtin_nontemporal_load(s + 3);
  char* sb = (char*)stg;
  const int b = lin * 2;
  *(short8*)(sb + ((b     ) ^ sw)) = v0;
  *(short8*)(sb + ((b + 16) ^ sw)) = v1;
  *(short8*)(sb + ((b + 32) ^ sw)) = v2;
  *(short8*)(sb + ((b + 48) ^ sw)) = v3;
}

// ---- publish 16B/thread write-through to MALL (sc0 sc1): one wide op per 16B ----
static __device__ __forceinline__ void pub16(unsigned short* dst, const unsigned short* lds_src){
  i32x4 v = *(const i32x4*)lds_src;
  asm volatile("global_store_dwordx4 %0, %1, off sc0 sc1" :: "v"(dst), "v"(v) : "memory");
}

// ---------------- persistent GRU scan: 4 row-groups x 8 col-slices ----------------
__global__ __launch_bounds__(512, 1) void gru_scan_k(
    const unsigned short* __restrict__ G2,    // [512][3][1024][64] bf16
    const unsigned short* __restrict__ wt,    // [6][1024][1024] bf16 [n][k]
    float* __restrict__ out,                  // [T][64][1024] fp32 + [64][1024] H_final
    unsigned short* __restrict__ hb,          // [NSLOT][4][16][1024] bf16 H slots
    unsigned short* __restrict__ rh,          // [NSLOT][4][16][1024] bf16 R*H slots
    int* __restrict__ flags)                  // [32 * 32] (128B-strided flags)
{
  __shared__ __align__(16) unsigned short stage[16 * 1024];  // 32 KiB staged H or R*H
  __shared__ __align__(16) unsigned short ostage[16 * 128];  // 4 KiB publish slice
  __shared__ float hlds[16 * 128];                           // own-slice H fp32
  __shared__ float zlds[16 * 128];                           // own-slice Z fp32

  const int bid = blockIdx.x;
  const int rg  = bid & 3;          // row-group: batch rows [rg*16, +16)
  const int cs  = bid >> 2;         // col-slice: hid cols  [cs*128, +128)
  const int tid  = threadIdx.x;
  const int wave = tid >> 6;
  const int lane = tid & 63;
  const int l16  = lane & 15;
  const int kq   = lane >> 4;
  const bool zp  = wave < 4;        // phase A: waves 0-3 Z, 4-7 R
  const int w3   = wave & 3;
  const int rowj0 = kq * 4;

  int* fgrp   = flags + rg * 8 * 32;
  int* myflag = fgrp + cs * 32;

  const int nA0 = cs * 128 + w3 * 32 + l16;
  const int nB  = cs * 128 + wave * 16 + l16;

  const unsigned short* wbA0 = wt + (size_t)(zp ? 1 : 3) * HID * HID + (size_t)nA0 * HID + kq * 8;
  const unsigned short* wbA1 = wbA0 + (size_t)16 * HID;
  const unsigned short* wbB  = wt + (size_t)5 * HID * HID + (size_t)nB * HID + kq * 8;

  const int abase = l16 * 2048 + kq * 16;     // byte base of A-frag in stage
  const int asw   = (l16 & 7) << 4;

  // publish geometry: tid<256 store 16B each of the [16][128] ostage
  const int p16  = tid * 8;                   // shorts
  const int prow = p16 >> 7, pcol = p16 & 127;
  const int pdst_off = prow * 1024 + cs * 128 + pcol;   // within this rg's [16][1024]

  float h[4] = {0.f, 0.f, 0.f, 0.f};

  for (int t = 0; t < T_STEPS; ++t){
    // rotating slots: write slot t, read H from slot t-1, R*H from slot t
    unsigned short* hb_w = hb + (size_t)(t & (NSLOT - 1)) * SLOT_SH + rg * 16384;
    unsigned short* rh_w = rh + (size_t)(t & (NSLOT - 1)) * SLOT_SH + rg * 16384;
    const unsigned short* hb_r = hb + (size_t)((t - 1) & (NSLOT - 1)) * SLOT_SH + rg * 16384;

    // ---- early (pre-wait) cached loads of this step's x-gate values ----
    const size_t gstep = (size_t)t * 3 * 1024 * 64;
    unsigned long long u0 = *(const unsigned long long*)
        (G2 + gstep + ((size_t)(zp ? 0 : 1) * 1024 + nA0) * 64 + rg * 16 + rowj0);
    unsigned long long u1 = *(const unsigned long long*)
        (G2 + gstep + ((size_t)(zp ? 0 : 1) * 1024 + nA0 + 16) * 64 + rg * 16 + rowj0);
    unsigned long long u2 = *(const unsigned long long*)
        (G2 + gstep + ((size_t)2 * 1024 + nB) * 64 + rg * 16 + rowj0);

    // ---- phase A: Z (waves 0-3) / R (waves 4-7) over this slice ----
    f32x4 a00 = {0,0,0,0}, a01 = {0,0,0,0}, a10 = {0,0,0,0}, a11 = {0,0,0,0};
    if (t){
      if (wave == 0) waitflags8(fgrp, 2 * t);      // H_{t-1} published by row-group
      __syncthreads();
      stage_in(hb_r, stage, tid);
      __syncthreads();
      const char* sb = (const char*)stage;
      #pragma unroll 4
      for (int c = 0; c < 32; c += 2){
        short8 af0 = *(const short8*)(sb + ((abase + c * 64) ^ asw));
        short8 af1 = *(const short8*)(sb + ((abase + c * 64 + 64) ^ asw));
        a00 = MFMA(af0, *(const short8*)(wbA0 + c * 32),      a00, 0, 0, 0);
        a01 = MFMA(af1, *(const short8*)(wbA0 + c * 32 + 32), a01, 0, 0, 0);
        a10 = MFMA(af0, *(const short8*)(wbA1 + c * 32),      a10, 0, 0, 0);
        a11 = MFMA(af1, *(const short8*)(wbA1 + c * 32 + 32), a11, 0, 0, 0);
      }
    }
    #pragma unroll
    for (int j = 0; j < 4; ++j){
      float g0 = sigm(a00[j] + a01[j] + b2f((unsigned short)(u0 >> (16 * j))));
      float g1 = sigm(a10[j] + a11[j] + b2f((unsigned short)(u1 >> (16 * j))));
      int i0 = (rowj0 + j) * 128 + w3 * 32 + l16;
      if (zp){
        zlds[i0] = g0; zlds[i0 + 16] = g1;
      } else {
        float hp0 = t ? hlds[i0] : 0.f;
        float hp1 = t ? hlds[i0 + 16] : 0.f;
        ostage[i0] = f2b(g0 * hp0); ostage[i0 + 16] = f2b(g1 * hp1);
      }
    }
    __syncthreads();                                  // zlds / ostage complete
    if (t){
      if (tid < 256) pub16(rh_w + pdst_off, &ostage[p16]);   // R*H -> slot t (MALL)
      __syncthreads();                                // every wave drains its stores
      if (tid == 0){
        asm volatile("s_waitcnt vmcnt(0)" ::: "memory");
        __hip_atomic_store(myflag, 2 * t + 1, __ATOMIC_RELAXED, __HIP_MEMORY_SCOPE_AGENT);
      }
    }

    // ---- phase B: H_tilde + combine, all 8 waves (16 cols each) ----
    f32x4 c0 = {0,0,0,0}, c1 = {0,0,0,0};
    if (t){
      if (wave == 0) waitflags8(fgrp, 2 * t + 1);     // R*H published by row-group
      __syncthreads();
      stage_in(rh_w, stage, tid);
      __syncthreads();
      const char* sb = (const char*)stage;
      #pragma unroll 4
      for (int c = 0; c < 32; c += 2){
        short8 af0 = *(const short8*)(sb + ((abase + c * 64) ^ asw));
        short8 af1 = *(const short8*)(sb + ((abase + c * 64 + 64) ^ asw));
        c0 = MFMA(af0, *(const short8*)(wbB + c * 32),      c0, 0, 0, 0);
        c1 = MFMA(af1, *(const short8*)(wbB + c * 32 + 32), c1, 0, 0, 0);
      }
    }
    #pragma unroll
    for (int j = 0; j < 4; ++j){
      int ib = (rowj0 + j) * 128 + wave * 16 + l16;
      float ht = tanh_fast(c0[j] + c1[j] + b2f((unsigned short)(u2 >> (16 * j))));
      float z  = zlds[ib];
      float hn = z * h[j] + (1.0f - z) * ht;
      h[j] = hn;
      hlds[ib] = hn;
      ostage[ib] = f2b(hn);
    }
    __syncthreads();                                  // ostage / hlds complete
    if (t < T_STEPS - 1){
      if (tid < 256) pub16(hb_w + pdst_off, &ostage[p16]);   // H_t -> slot t (MALL)
      __syncthreads();
      if (tid == 0){
        asm volatile("s_waitcnt vmcnt(0)" ::: "memory");
        __hip_atomic_store(myflag, 2 * t + 2, __ATOMIC_RELAXED, __HIP_MEMORY_SCOPE_AGENT);
      }
    }
    // out stores: off the critical path, never read by other WGs
    #pragma unroll
    for (int j = 0; j < 4; ++j){
      __builtin_nontemporal_store(h[j], &out[((size_t)t * BATCH + rg * 16 + rowj0 + j) * HID + nB]);
      if (t == T_STEPS - 1)
        __builtin_nontemporal_store(h[j],
            &out[(size_t)T_STEPS * BATCH * HID + (size_t)(rg * 16 + rowj0 + j) * HID + nB]);
    }
  }
}

extern "C" void kernel_launch(void* const* d_in, const int* in_sizes, int n_in,
                              void* d_out, int out_size, void* d_ws, size_t ws_size,
                              hipStream_t stream){
  const float* inputs = (const float*)d_in[0];
  const float* W_xz = (const float*)d_in[1];
  const float* W_hz = (const float*)d_in[2];
  const float* b_z  = (const float*)d_in[3];
  const float* W_xr = (const float*)d_in[4];
  const float* W_hr = (const float*)d_in[5];
  const float* b_r  = (const float*)d_in[6];
  const float* W_xh = (const float*)d_in[7];
  const float* W_hh = (const float*)d_in[8];
  const float* b_h  = (const float*)d_in[9];
  float* out = (float*)d_out;

  char* ws = (char*)d_ws;
  int*            flags = (int*)ws;                                  // 4 KiB (128B-strided)
  unsigned short* hb    = (unsigned short*)(ws + 4096);              // 4 MiB (32 slots)
  unsigned short* rh    = (unsigned short*)(ws + 4096 + 4194304);    // 4 MiB
  unsigned short* wt    = (unsigned short*)(ws + 4096 + 8388608);    // 12 MiB
  unsigned short* G2    = (unsigned short*)(ws + 4096 + 8388608 + 12582912); // 192 MiB
  // total ws needed: ~212 MB

  gru_init_k<<<4, 256, 0, stream>>>(flags);
  gru_prepw_k<<<dim3(32, 32, 6), dim3(32, 8), 0, stream>>>(W_xz, W_hz, W_xr, W_hr, W_xh, W_hh, wt);
  gru_xproj_k<<<dim3(512, 12), 256, 0, stream>>>(inputs, wt, b_z, b_r, b_h, G2);
  gru_scan_k<<<NWG, 512, 0, stream>>>(G2, wt, out, hb, rh, flags);
}

// Round 13
// 4672.514 us; speedup vs baseline: 5.2240x; 3.2545x over previous
//
#include <hip/hip_runtime.h>
#include <hip/hip_bf16.h>

#define T_STEPS 512
#define BATCH   64
#define HID     1024
#define NWG     128         // 4 row-groups x 32 col-slices (32 cols each)
#define NSLOT   32          // rotating exchange slots
#define SLOT_SH (4 * 16 * 1024)   // shorts per slot

typedef __attribute__((ext_vector_type(8))) short short8;
typedef __attribute__((ext_vector_type(4))) float f32x4;
typedef __attribute__((ext_vector_type(4))) int  i32x4;

static __device__ __forceinline__ float b2f(unsigned short u){
  union { unsigned u; float f; } c; c.u = ((unsigned)u) << 16; return c.f;
}
static __device__ __forceinline__ unsigned short f2b(float f){
  union { float f; unsigned u; } c; c.f = f;
  unsigned r = c.u + 0x7fffu + ((c.u >> 16) & 1u);
  return (unsigned short)(r >> 16);
}
static __device__ __forceinline__ float sigm(float x){ return 1.0f / (1.0f + __expf(-x)); }
static __device__ __forceinline__ float tanh_fast(float x){ return 2.0f / (1.0f + __expf(-2.0f * x)) - 1.0f; }

#define MFMA __builtin_amdgcn_mfma_f32_16x16x32_bf16

// ---------------- init: zero barrier flags (1 flag per 128B line) ----------------
__global__ void gru_init_k(int* __restrict__ flags){
  int i = blockIdx.x * blockDim.x + threadIdx.x;
  if (i < 4 * 32 * 32)
    __hip_atomic_store(flags + i, 0, __ATOMIC_RELAXED, __HIP_MEMORY_SCOPE_AGENT);
}

// ---------------- transpose + cast weights: Wt[g][n][k] = W_g[k][n] ----------------
__global__ void gru_prepw_k(const float* __restrict__ w0, const float* __restrict__ w1,
                            const float* __restrict__ w2, const float* __restrict__ w3,
                            const float* __restrict__ w4, const float* __restrict__ w5,
                            unsigned short* __restrict__ wt){
  __shared__ float tile[32][33];
  const float* src;
  switch (blockIdx.z){
    case 0: src = w0; break; case 1: src = w1; break; case 2: src = w2; break;
    case 3: src = w3; break; case 4: src = w4; break; default: src = w5; break;
  }
  int tx = threadIdx.x, ty = threadIdx.y;
  int x0 = blockIdx.x * 32, y0 = blockIdx.y * 32;
  #pragma unroll
  for (int i = 0; i < 32; i += 8)
    tile[ty + i][tx] = src[(size_t)(y0 + ty + i) * HID + x0 + tx];
  __syncthreads();
  unsigned short* dst = wt + (size_t)blockIdx.z * HID * HID;
  #pragma unroll
  for (int i = 0; i < 32; i += 8)
    dst[(size_t)(x0 + ty + i) * HID + y0 + tx] = f2b(tile[tx][ty + i]);
}

// ---------------- pre-pass: G2[t][gate][col][row] = (X @ Wx + b), bf16 ----------
__global__ __launch_bounds__(256, 2) void gru_xproj_k(
    const float* __restrict__ inp,         // [32768][1024] fp32
    const unsigned short* __restrict__ wt, // x-weights slots 0,2,4
    const float* __restrict__ bz, const float* __restrict__ br, const float* __restrict__ bh,
    unsigned short* __restrict__ G2)       // [512][3][1024][64] bf16
{
  const int wv = threadIdx.x >> 6, lane = threadIdx.x & 63;
  const int l16 = lane & 15, kq = lane >> 4;
  const int m0 = blockIdx.x * 64;
  const int n0 = blockIdx.y * 256 + wv * 64;

  const unsigned short* wb[4];
  float bias[4];
  #pragma unroll
  for (int c = 0; c < 4; ++c){
    int n = n0 + c * 16 + l16;
    int g = n >> 10, cc = n & 1023;
    wb[c] = wt + (size_t)(2 * g) * HID * HID + (size_t)cc * HID + kq * 8;
    bias[c] = (g == 0 ? bz : (g == 1 ? br : bh))[cc];
  }
  const float* arow[4];
  #pragma unroll
  for (int r = 0; r < 4; ++r)
    arow[r] = inp + (size_t)(m0 + r * 16 + l16) * HID + kq * 8;

  f32x4 acc[4][4];
  #pragma unroll
  for (int r = 0; r < 4; ++r)
    #pragma unroll
    for (int c = 0; c < 4; ++c) acc[r][c] = (f32x4){0.f,0.f,0.f,0.f};

  #pragma unroll 2
  for (int kk = 0; kk < HID; kk += 32){
    short8 af[4], bf[4];
    #pragma unroll
    for (int r = 0; r < 4; ++r){
      float4 f0 = *(const float4*)(arow[r] + kk);
      float4 f1 = *(const float4*)(arow[r] + kk + 4);
      short8 a;
      a[0]=(short)f2b(f0.x); a[1]=(short)f2b(f0.y); a[2]=(short)f2b(f0.z); a[3]=(short)f2b(f0.w);
      a[4]=(short)f2b(f1.x); a[5]=(short)f2b(f1.y); a[6]=(short)f2b(f1.z); a[7]=(short)f2b(f1.w);
      af[r] = a;
    }
    #pragma unroll
    for (int c = 0; c < 4; ++c) bf[c] = *(const short8*)(wb[c] + kk);
    #pragma unroll
    for (int r = 0; r < 4; ++r)
      #pragma unroll
      for (int c = 0; c < 4; ++c)
        acc[r][c] = MFMA(af[r], bf[c], acc[r][c], 0, 0, 0);
  }

  #pragma unroll
  for (int c = 0; c < 4; ++c){
    int n = n0 + c * 16 + l16;
    int g = n >> 10, cc = n & 1023;
    #pragma unroll
    for (int r = 0; r < 4; ++r){
      unsigned lo = (unsigned)f2b(acc[r][c][0] + bias[c]) | ((unsigned)f2b(acc[r][c][1] + bias[c]) << 16);
      unsigned hi = (unsigned)f2b(acc[r][c][2] + bias[c]) | ((unsigned)f2b(acc[r][c][3] + bias[c]) << 16);
      *(unsigned long long*)&G2[((size_t)(blockIdx.x * 3 + g) * 1024 + cc) * 64 + r * 16 + kq * 4] =
        (unsigned long long)lo | ((unsigned long long)hi << 32);
    }
  }
}

// ---- poll: 32 lanes, one flag each (flags 128B apart), s_sleep backoff ----
static __device__ __forceinline__ void waitflags32(const int* fgrp, int target){
  const int lane = threadIdx.x & 63;
  const int* p = fgrp + (lane & 31) * 32;
  const bool mine = lane < 32;
  for (;;){
    int v = mine ? __hip_atomic_load(p, __ATOMIC_RELAXED, __HIP_MEMORY_SCOPE_AGENT)
                 : 0x7fffffff;
    if (__all(v >= target)) return;
    __builtin_amdgcn_s_sleep(2);
  }
}

// ---- stage 16x1024 bf16 tile (32KB) via cached nontemporal loads (fresh slot lines) ----
static __device__ __forceinline__ void stage_in(const unsigned short* __restrict__ src,
                                                unsigned short* __restrict__ stg, int tid){
  const int lin = tid * 32;                 // shorts (64B per thread)
  const int sw  = ((tid >> 5) & 7) << 4;    // byte XOR (row&7)<<4
  const short8* s = (const short8*)(src + lin);
  short8 v0 = __builtin_nontemporal_load(s);
  short8 v1 = __builtin_nontemporal_load(s + 1);
  short8 v2 = __builtin_nontemporal_load(s + 2);
  short8 v3 = __builtin_nontemporal_load(s + 3);
  char* sb = (char*)stg;
  const int b = lin * 2;
  *(short8*)(sb + ((b     ) ^ sw)) = v0;
  *(short8*)(sb + ((b + 16) ^ sw)) = v1;
  *(short8*)(sb + ((b + 32) ^ sw)) = v2;
  *(short8*)(sb + ((b + 48) ^ sw)) = v3;
}

// ---- publish 16B write-through to MALL (sc0 sc1) ----
static __device__ __forceinline__ void pub16(unsigned short* dst, const unsigned short* lds_src){
  i32x4 v = *(const i32x4*)lds_src;
  asm volatile("global_store_dwordx4 %0, %1, off sc0 sc1" :: "v"(dst), "v"(v) : "memory");
}

// ---------------- persistent GRU scan: 4 rg x 32 cs, weights in VGPRs ----------------
__global__ __launch_bounds__(512, 1) void gru_scan_k(
    const unsigned short* __restrict__ G2,    // [512][3][1024][64] bf16
    const unsigned short* __restrict__ wt,    // [6][1024][1024] bf16 [n][k]
    float* __restrict__ out,                  // [T][64][1024] fp32 + [64][1024] H_final
    unsigned short* __restrict__ hb,          // [NSLOT][4][16][1024] bf16 H slots
    unsigned short* __restrict__ rh,          // [NSLOT][4][16][1024] bf16 R*H slots
    int* __restrict__ flags)                  // [4][32][32] (128B-strided flags)
{
  __shared__ __align__(16) unsigned short stage[16 * 1024];  // 32 KiB staged H or R*H
  __shared__ float pbuf[2048];                               // 8 KiB split-K partials
  __shared__ float zlds[512];                                // own-slice Z [16][32]
  __shared__ float hlds[512];                                // own-slice H fp32
  __shared__ __align__(16) unsigned short ostage[512];       // 1 KiB publish tile

  const int bid = blockIdx.x;
  const int rg  = bid & 3;            // batch rows [rg*16, +16)
  const int cs  = bid >> 2;           // hid cols  [cs*32, +32)
  const int tid  = threadIdx.x;
  const int w    = tid >> 6;
  const int lane = tid & 63;
  const int l16  = lane & 15;
  const int kq   = lane >> 4;

  // phase-A role: gate (Z/R) x col-tile x K-half.  phase-B role: col-tile x K-quarter.
  const int gA = w & 1, ctA = (w >> 1) & 1, khA = w >> 2;
  const int ctB = w & 1, kqB = w >> 1;

  // reduce mapping: one thread per own-slice element
  const int rrow = tid >> 5, rcol = tid & 31;
  const int gcr  = cs * 32 + rcol;          // global hidden col
  const int grow = rg * 16 + rrow;          // global batch row

  // ---- preload this WG's weight slice into registers (once; never re-read) ----
  short8 wA[16];
  {
    const unsigned short* p = wt + (size_t)(gA ? 3 : 1) * HID * HID
                            + (size_t)(cs * 32 + ctA * 16 + l16) * HID + khA * 512 + kq * 8;
    #pragma unroll
    for (int i = 0; i < 16; ++i) wA[i] = *(const short8*)(p + i * 32);
  }
  short8 wB[8];
  {
    const unsigned short* p = wt + (size_t)5 * HID * HID
                            + (size_t)(cs * 32 + ctB * 16 + l16) * HID + kqB * 256 + kq * 8;
    #pragma unroll
    for (int i = 0; i < 8; ++i) wB[i] = *(const short8*)(p + i * 32);
  }

  int* fgrp   = flags + rg * 32 * 32;
  int* myflag = fgrp + cs * 32;

  hlds[tid] = 0.f;
  __syncthreads();

  const int asw = (l16 & 7) << 4;
  const int aA  = l16 * 2048 + khA * 1024 + kq * 16;   // + i*64, then ^asw
  const int aB  = l16 * 2048 + kqB * 512  + kq * 16;

  const int prow64 = tid >> 2, pc8 = (tid & 3) * 8;    // publish mapping (tid<64)

  for (int t = 0; t < T_STEPS; ++t){
    unsigned short* hb_w = hb + (size_t)(t & (NSLOT - 1)) * SLOT_SH + rg * 16384;
    unsigned short* rh_w = rh + (size_t)(t & (NSLOT - 1)) * SLOT_SH + rg * 16384;
    const unsigned short* hb_r = hb + (size_t)((t - 1) & (NSLOT - 1)) * SLOT_SH + rg * 16384;

    // prefetch x-gate scalars (cached; before any wait)
    const size_t gstep = (size_t)t * 3 * 1024 * 64;
    const float gxz = b2f(G2[gstep + ((size_t)0 * 1024 + gcr) * 64 + grow]);
    const float gxr = b2f(G2[gstep + ((size_t)1 * 1024 + gcr) * 64 + grow]);
    const float gxh = b2f(G2[gstep + ((size_t)2 * 1024 + gcr) * 64 + grow]);

    // ---- phase A: H_{t-1} @ {Whz,Whr} (split gate/ct/khalf across 8 waves) ----
    if (t){
      if (w == 0) waitflags32(fgrp, 2 * t);
      __syncthreads();
      stage_in(hb_r, stage, tid);
      __syncthreads();
      const char* sb = (const char*)stage;
      f32x4 acc = {0.f, 0.f, 0.f, 0.f};
      #pragma unroll
      for (int i = 0; i < 16; ++i){
        short8 af = *(const short8*)(sb + ((aA + i * 64) ^ asw));
        acc = MFMA(af, wA[i], acc, 0, 0, 0);
      }
      #pragma unroll
      for (int j = 0; j < 4; ++j)
        pbuf[((gA * 2 + khA) * 2 + ctA) * 256 + (kq * 4 + j) * 16 + l16] = acc[j];
    }
    __syncthreads();                                   // pbuf ready (or t==0)
    {
      const int ct = rcol >> 4, eidx = rrow * 16 + (rcol & 15);
      float pz = t ? (pbuf[(0 + ct) * 256 + eidx] + pbuf[(2 + ct) * 256 + eidx]) : 0.f;
      float pr = t ? (pbuf[(4 + ct) * 256 + eidx] + pbuf[(6 + ct) * 256 + eidx]) : 0.f;
      float z  = sigm(pz + gxz);
      float r  = sigm(pr + gxr);
      zlds[tid]   = z;
      ostage[tid] = f2b(r * hlds[tid]);
    }
    __syncthreads();                                   // ostage ready; pbuf reusable
    if (t){
      if (tid < 64) pub16(rh_w + prow64 * 1024 + cs * 32 + pc8, &ostage[prow64 * 32 + pc8]);
      __syncthreads();                                 // publish drained (per-wave vmcnt)
      if (tid == 0){
        asm volatile("s_waitcnt vmcnt(0)" ::: "memory");
        __hip_atomic_store(myflag, 2 * t + 1, __ATOMIC_RELAXED, __HIP_MEMORY_SCOPE_AGENT);
      }
      // ---- phase B: (R*H) @ Whh (split ct/kquarter across 8 waves) ----
      if (w == 0) waitflags32(fgrp, 2 * t + 1);
      __syncthreads();
      stage_in(rh_w, stage, tid);
      __syncthreads();
      const char* sb = (const char*)stage;
      f32x4 acc = {0.f, 0.f, 0.f, 0.f};
      #pragma unroll
      for (int i = 0; i < 8; ++i){
        short8 af = *(const short8*)(sb + ((aB + i * 64) ^ asw));
        acc = MFMA(af, wB[i], acc, 0, 0, 0);
      }
      #pragma unroll
      for (int j = 0; j < 4; ++j)
        pbuf[(kqB * 2 + ctB) * 256 + (kq * 4 + j) * 16 + l16] = acc[j];
    }
    __syncthreads();
    {
      const int ct = rcol >> 4, eidx = rrow * 16 + (rcol & 15);
      float ph = t ? (pbuf[(0 + ct) * 256 + eidx] + pbuf[(2 + ct) * 256 + eidx]
                    + pbuf[(4 + ct) * 256 + eidx] + pbuf[(6 + ct) * 256 + eidx]) : 0.f;
      float ht = tanh_fast(ph + gxh);
      float z  = zlds[tid], hp = hlds[tid];
      float hn = z * hp + (1.0f - z) * ht;
      hlds[tid]   = hn;
      ostage[tid] = f2b(hn);
      __builtin_nontemporal_store(hn, &out[((size_t)t * BATCH + grow) * HID + gcr]);
      if (t == T_STEPS - 1)
        __builtin_nontemporal_store(hn, &out[(size_t)T_STEPS * BATCH * HID + (size_t)grow * HID + gcr]);
    }
    __syncthreads();                                   // ostage/hlds complete
    if (t < T_STEPS - 1){
      if (tid < 64) pub16(hb_w + prow64 * 1024 + cs * 32 + pc8, &ostage[prow64 * 32 + pc8]);
      __syncthreads();
      if (tid == 0){
        asm volatile("s_waitcnt vmcnt(0)" ::: "memory");
        __hip_atomic_store(myflag, 2 * t + 2, __ATOMIC_RELAXED, __HIP_MEMORY_SCOPE_AGENT);
      }
    }
  }
}

extern "C" void kernel_launch(void* const* d_in, const int* in_sizes, int n_in,
                              void* d_out, int out_size, void* d_ws, size_t ws_size,
                              hipStream_t stream){
  const float* inputs = (const float*)d_in[0];
  const float* W_xz = (const float*)d_in[1];
  const float* W_hz = (const float*)d_in[2];
  const float* b_z  = (const float*)d_in[3];
  const float* W_xr = (const float*)d_in[4];
  const float* W_hr = (const float*)d_in[5];
  const float* b_r  = (const float*)d_in[6];
  const float* W_xh = (const float*)d_in[7];
  const float* W_hh = (const float*)d_in[8];
  const float* b_h  = (const float*)d_in[9];
  float* out = (float*)d_out;

  char* ws = (char*)d_ws;
  int*            flags = (int*)ws;                                  // 16 KiB (128B-strided)
  unsigned short* hb    = (unsigned short*)(ws + 16384);             // 4 MiB (32 slots)
  unsigned short* rh    = (unsigned short*)(ws + 16384 + 4194304);   // 4 MiB
  unsigned short* wt    = (unsigned short*)(ws + 16384 + 8388608);   // 12 MiB
  unsigned short* G2    = (unsigned short*)(ws + 16384 + 8388608 + 12582912); // 192 MiB
  // total ws needed: ~212 MB

  gru_init_k<<<16, 256, 0, stream>>>(flags);
  gru_prepw_k<<<dim3(32, 32, 6), dim3(32, 8), 0, stream>>>(W_xz, W_hz, W_xr, W_hr, W_xh, W_hh, wt);
  gru_xproj_k<<<dim3(512, 12), 256, 0, stream>>>(inputs, wt, b_z, b_r, b_h, G2);
  gru_scan_k<<<NWG, 512, 0, stream>>>(G2, wt, out, hb, rh, flags);
}